// Round 7
// baseline (526.989 us; speedup 1.0000x reference)
//
#include <hip/hip_runtime.h>
#include <hip/hip_bf16.h>

#define NFEAT 128
#define HID 256
#define BN_EPS 1e-5f

typedef __attribute__((ext_vector_type(8))) __bf16 bf16x8;
typedef __attribute__((ext_vector_type(4))) float f32x4;

static __device__ __forceinline__ float bflo(unsigned u) {
    union { unsigned x; float f; } c; c.x = u << 16; return c.f;
}
static __device__ __forceinline__ float bfhi(unsigned u) {
    union { unsigned x; float f; } c; c.x = u & 0xffff0000u; return c.f;
}
static __device__ __forceinline__ float bf2f(__hip_bfloat16 v) { return __bfloat162float(v); }

// ---------- CSR build ----------
__global__ void k_count(const int* __restrict__ ei, int E, int* __restrict__ cnt,
                        int* __restrict__ rank) {
    int e = blockIdx.x * blockDim.x + threadIdx.x;
    if (e < E) rank[e] = atomicAdd(&cnt[ei[E + e]], 1);
}

__global__ void k_scan1(const int* __restrict__ cnt, int n, int* __restrict__ partial,
                        int* __restrict__ blk_total) {
    __shared__ int sh[256];
    int i = blockIdx.x * 256 + threadIdx.x;
    int v = (i < n) ? cnt[i] : 0;
    sh[threadIdx.x] = v;
    __syncthreads();
    for (int off = 1; off < 256; off <<= 1) {
        int x = (threadIdx.x >= off) ? sh[threadIdx.x - off] : 0;
        __syncthreads();
        sh[threadIdx.x] += x;
        __syncthreads();
    }
    if (i < n) partial[i] = sh[threadIdx.x] - v;
    if (threadIdx.x == 255) blk_total[blockIdx.x] = sh[255];
}

__global__ void k_scan2(int* __restrict__ blk, int nb) {
    __shared__ int sh[256];
    int t = threadIdx.x;
    int v = (t < nb) ? blk[t] : 0;
    sh[t] = v;
    __syncthreads();
    for (int off = 1; off < 256; off <<= 1) {
        int x = (t >= off) ? sh[t - off] : 0;
        __syncthreads();
        sh[t] += x;
        __syncthreads();
    }
    if (t < nb) blk[t] = sh[t] - v;
}

__global__ void k_finalize(const int* __restrict__ partial, const int* __restrict__ blk,
                           const int* __restrict__ cnt, int n, int* __restrict__ row_start,
                           float* __restrict__ dinv) {
    int i = blockIdx.x * blockDim.x + threadIdx.x;
    if (i < n) {
        row_start[i] = partial[i] + blk[i >> 8];
        dinv[i] = rsqrtf((float)(cnt[i] + 1));
    }
}

__global__ void k_fill(const int* __restrict__ ei, const int* __restrict__ rank,
                       const int* __restrict__ row_start, int E, int* __restrict__ col) {
    int e = blockIdx.x * blockDim.x + threadIdx.x;
    if (e < E) {
        int d = ei[E + e];
        col[row_start[d] + rank[e]] = ei[e];
    }
}

// ---------- fp32 -> bf16 cast with per-row dinv scale ----------
__global__ void k_scale_cast(const float* __restrict__ in, const float* __restrict__ dinv,
                             __hip_bfloat16* __restrict__ out, int shift, int n4) {
    int i = blockIdx.x * blockDim.x + threadIdx.x;
    if (i < n4) {
        float d = dinv[i >> shift];
        float4 v = *(const float4*)(in + (size_t)i * 4);
        __hip_bfloat16* o = out + (size_t)i * 4;
        o[0] = __float2bfloat16(v.x * d);
        o[1] = __float2bfloat16(v.y * d);
        o[2] = __float2bfloat16(v.z * d);
        o[3] = __float2bfloat16(v.w * d);
    }
}

// ---------- W2/Wfc transpose+cast ----------
__global__ void k_transpose2(const float* __restrict__ W2, const float* __restrict__ Wf,
                             __hip_bfloat16* __restrict__ Wt2, __hip_bfloat16* __restrict__ Wtf) {
    int idx = blockIdx.x * 256 + threadIdx.x;  // 0..131071
    const float* W;
    __hip_bfloat16* Wt;
    int base;
    if (idx < 65536) { W = W2; Wt = Wt2; base = idx; }
    else { W = Wf; Wt = Wtf; base = idx - 65536; }
    int n = base & 255;
    int k = base >> 8;
    Wt[n * 256 + k] = __float2bfloat16(W[k * 256 + n]);
}

// ---------- SpMM1: aggX_i = di*(xs_i + sum xs_j); p_i = di*aggX_i ----------
__global__ __launch_bounds__(256) void k_spmm1(const __hip_bfloat16* __restrict__ xs,
                                               const int* __restrict__ rs,
                                               const int* __restrict__ rc,
                                               const int* __restrict__ col,
                                               const float* __restrict__ dinv,
                                               __hip_bfloat16* __restrict__ aggX,
                                               __hip_bfloat16* __restrict__ p, int N) {
    const int wid = blockIdx.x * 4 + (threadIdx.x >> 6);
    if (wid >= N) return;
    const int lane = threadIdx.x & 63;
    const int ch = lane * 2;
    const int s = rs[wid];
    const int deg = rc[wid];
    const float di = dinv[wid];

    unsigned u0 = *(const unsigned*)(xs + (size_t)wid * 128 + ch);
    float a0 = bflo(u0), a1 = bfhi(u0);
    int e = 0;
    for (; e + 16 <= deg; e += 16) {
        int idx[16];
#pragma unroll
        for (int j = 0; j < 16; j++) idx[j] = col[s + e + j];
        unsigned v[16];
#pragma unroll
        for (int j = 0; j < 16; j++) v[j] = *(const unsigned*)(xs + (size_t)idx[j] * 128 + ch);
#pragma unroll
        for (int j = 0; j < 16; j++) { a0 += bflo(v[j]); a1 += bfhi(v[j]); }
    }
    for (; e < deg; e++) {
        int i0 = col[s + e];
        unsigned v0 = *(const unsigned*)(xs + (size_t)i0 * 128 + ch);
        a0 += bflo(v0);
        a1 += bfhi(v0);
    }
    float o0 = di * a0, o1 = di * a1;
    union { unsigned u; unsigned short us[2]; } oa, op;
    __hip_bfloat16 b;
    b = __float2bfloat16(o0); oa.us[0] = *(unsigned short*)&b;
    b = __float2bfloat16(o1); oa.us[1] = *(unsigned short*)&b;
    b = __float2bfloat16(di * o0); op.us[0] = *(unsigned short*)&b;
    b = __float2bfloat16(di * o1); op.us[1] = *(unsigned short*)&b;
    *(unsigned*)(aggX + (size_t)wid * 128 + ch) = oa.u;
    *(unsigned*)(p + (size_t)wid * 128 + ch) = op.u;
}

// ---------- SpMM2: r_i = di*(p_i + sum p_j); s_i = di*(di + sum dinv_j) ----------
__global__ __launch_bounds__(256) void k_spmm2(const __hip_bfloat16* __restrict__ p,
                                               const int* __restrict__ rs,
                                               const int* __restrict__ rc,
                                               const int* __restrict__ col,
                                               const float* __restrict__ dinv,
                                               __hip_bfloat16* __restrict__ r_out,
                                               float* __restrict__ s_out, int N) {
    const int wid = blockIdx.x * 4 + (threadIdx.x >> 6);
    if (wid >= N) return;
    const int lane = threadIdx.x & 63;
    const int ch = lane * 2;
    const int s = rs[wid];
    const int deg = rc[wid];
    const float di = dinv[wid];

    unsigned u0 = *(const unsigned*)(p + (size_t)wid * 128 + ch);
    float a0 = bflo(u0), a1 = bfhi(u0);
    float dsum = 0.f;
    int e = 0;
    for (; e + 16 <= deg; e += 16) {
        int idx[16];
#pragma unroll
        for (int j = 0; j < 16; j++) idx[j] = col[s + e + j];
        unsigned v[16];
        float dv[16];
#pragma unroll
        for (int j = 0; j < 16; j++) {
            v[j] = *(const unsigned*)(p + (size_t)idx[j] * 128 + ch);
            dv[j] = dinv[idx[j]];
        }
#pragma unroll
        for (int j = 0; j < 16; j++) { a0 += bflo(v[j]); a1 += bfhi(v[j]); dsum += dv[j]; }
    }
    for (; e < deg; e++) {
        int i0 = col[s + e];
        unsigned v0 = *(const unsigned*)(p + (size_t)i0 * 128 + ch);
        a0 += bflo(v0);
        a1 += bfhi(v0);
        dsum += dinv[i0];
    }
    union { unsigned u; unsigned short us[2]; } o;
    __hip_bfloat16 b;
    b = __float2bfloat16(di * a0); o.us[0] = *(unsigned short*)&b;
    b = __float2bfloat16(di * a1); o.us[1] = *(unsigned short*)&b;
    *(unsigned*)(r_out + (size_t)wid * 128 + ch) = o.u;
    if (lane == 0) s_out[wid] = di * (di + dsum);
}

// ---------- column sums of aggX (for BN1 mean) ----------
__global__ __launch_bounds__(256) void k_colsum(const __hip_bfloat16* __restrict__ X, int N,
                                                float* __restrict__ colsum) {
    __shared__ float sd[256];
    int t = threadIdx.x;
    int ch = t & 127, half = t >> 7;
    float acc = 0.f;
    for (int r = blockIdx.x * 2 + half; r < N; r += 256) acc += bf2f(X[(size_t)r * 128 + ch]);
    sd[t] = acc;
    __syncthreads();
    if (t < 128) atomicAdd(&colsum[t], sd[t] + sd[t + 128]);
}

// ---------- Gram: Gpart[b] = sum over block's rows of aggX^T aggX (128x128) ----------
// Per 32-row chunk: stage transposed tile Xt[128][40] (stride 40 keeps b128 16B-aligned),
// then A-frag and B-frag have IDENTICAL lane addressing (both [ch][k] layout) -> 8 frag
// reads feed 16 MFMAs/wave (wave w owns G-row-strips w and w+4).
__global__ __launch_bounds__(256) void k_gram(const __hip_bfloat16* __restrict__ X, int N,
                                              float* __restrict__ Gpart) {
    __shared__ __align__(16) unsigned short Xt[128 * 40];
    const int t = threadIdx.x;
    const int wv = t >> 6, lane = t & 63, mlane = lane & 15, quad = lane >> 4;
    const int srow = t & 31;
    const int scol = (t >> 5) * 16;
    const int r0 = blockIdx.x * 224;
    const int r1 = min(r0 + 224, N);

    f32x4 acc0[8], acc1[8];
#pragma unroll
    for (int i = 0; i < 8; i++) { acc0[i] = (f32x4){0,0,0,0}; acc1[i] = (f32x4){0,0,0,0}; }

    for (int rc = r0; rc < r1; rc += 32) {
        int grow = rc + srow;
        uint4 v0 = {0,0,0,0}, v1 = {0,0,0,0};
        if (grow < N) {
            v0 = *(const uint4*)(X + (size_t)grow * 128 + scol);
            v1 = *(const uint4*)(X + (size_t)grow * 128 + scol + 8);
        }
        __syncthreads();
        union { uint4 q[2]; unsigned short us[16]; } sv;
        sv.q[0] = v0; sv.q[1] = v1;
#pragma unroll
        for (int i = 0; i < 16; i++) Xt[(scol + i) * 40 + srow] = sv.us[i];
        __syncthreads();
        bf16x8 fa0 = *(const bf16x8*)(Xt + (wv * 16 + mlane) * 40 + quad * 8);
        bf16x8 fa1 = *(const bf16x8*)(Xt + ((wv + 4) * 16 + mlane) * 40 + quad * 8);
#pragma unroll
        for (int nt = 0; nt < 8; nt++) {
            bf16x8 fb = *(const bf16x8*)(Xt + (nt * 16 + mlane) * 40 + quad * 8);
            acc0[nt] = __builtin_amdgcn_mfma_f32_16x16x32_bf16(fa0, fb, acc0[nt], 0, 0, 0);
            acc1[nt] = __builtin_amdgcn_mfma_f32_16x16x32_bf16(fa1, fb, acc1[nt], 0, 0, 0);
        }
    }
    float* gp = Gpart + (size_t)blockIdx.x * 16384;
#pragma unroll
    for (int nt = 0; nt < 8; nt++)
#pragma unroll
        for (int rr = 0; rr < 4; rr++) {
            gp[(wv * 16 + quad * 4 + rr) * 128 + nt * 16 + mlane] = acc0[nt][rr];
            gp[((wv + 4) * 16 + quad * 4 + rr) * 128 + nt * 16 + mlane] = acc1[nt][rr];
        }
}

__global__ void k_gramred(const float* __restrict__ Gpart, float* __restrict__ G, int nb) {
    int i = blockIdx.x * 256 + threadIdx.x;  // 64 blocks -> 16384
    float acc = 0.f;
    for (int b = 0; b < nb; b++) acc += Gpart[(size_t)b * 16384 + i];
    G[i] = acc;
}

// ---------- BN1 coefficients from Gram; writes u[c] and W1s = W1*diag(sc1) (bf16) ----------
__global__ __launch_bounds__(128) void k_bncoef(const float* __restrict__ G,
                                                const float* __restrict__ colsum,
                                                const float* __restrict__ W1,
                                                const float* __restrict__ b1,
                                                const float* __restrict__ g1,
                                                const float* __restrict__ be1, float invN,
                                                float* __restrict__ u,
                                                __hip_bfloat16* __restrict__ W1s) {
    __shared__ float sw[128];
    __shared__ float red[128];
    __shared__ float red2[128];
    __shared__ float bc;
    const int c = blockIdx.x;
    const int k = threadIdx.x;
    float wk = W1[k * 256 + c];
    sw[k] = wk;
    __syncthreads();
    float gw = 0.f;
    for (int l = 0; l < 128; l++) gw += G[l * 128 + k] * sw[l];  // (Gw)_k via symmetry
    red[k] = gw * wk;
    red2[k] = colsum[k] * wk;
    __syncthreads();
    for (int off = 64; off; off >>= 1) {
        if (k < off) { red[k] += red[k + off]; red2[k] += red2[k + off]; }
        __syncthreads();
    }
    if (k == 0) {
        float wGw = red[0] * invN;
        float mux = red2[0] * invN;
        float b1c = b1[c];
        float Eh2 = wGw + 2.f * b1c * mux + b1c * b1c;
        float muh = mux + b1c;
        float var = Eh2 - muh * muh;
        float sc = g1[c] * rsqrtf(var + BN_EPS);
        float sh = be1[c] - muh * sc;
        u[c] = b1c * sc + sh;
        bc = sc;
    }
    __syncthreads();
    W1s[k * 256 + c] = __float2bfloat16(sw[k] * bc);
}

// ---------- c2 = u @ W2 ----------
__global__ void k_c2(const float* __restrict__ u, const float* __restrict__ W2,
                     float* __restrict__ c2) {
    __shared__ float su[256];
    int t = threadIdx.x;
    su[t] = u[t];
    __syncthreads();
    float acc = 0.f;
    for (int c = 0; c < 256; c++) acc += su[c] * W2[c * 256 + t];
    c2[t] = acc;
}

// ---------- fold BN2 into final weights: Wtf *= sc2[k]; cf = sh2@Wfc + bfc ----------
__global__ void k_bn2fold(const float* __restrict__ gsum, const float* __restrict__ gsq,
                          const float* __restrict__ g2, const float* __restrict__ be2,
                          const float* __restrict__ Wfc, const float* __restrict__ bfc,
                          float invN, __hip_bfloat16* __restrict__ Wtf, float* __restrict__ cf) {
    __shared__ float ssh[256];
    int t = threadIdx.x;
    float mean = gsum[t] * invN;
    float var = gsq[t] * invN - mean * mean;
    float sc = rsqrtf(var + BN_EPS) * g2[t];
    float sh = be2[t] - mean * sc;
    ssh[t] = sh;
    __syncthreads();
    for (int n = 0; n < 256; n++) {
        int idx = n * 256 + t;  // thread owns k=t -> scale by own sc
        Wtf[idx] = __float2bfloat16(bf2f(Wtf[idx]) * sc);
    }
    float acc = bfc[t];
    for (int k = 0; k < 256; k++) acc += ssh[k] * Wfc[k * 256 + t];
    cf[t] = acc;
}

// ---------- single-barrier MFMA GEMM (64 rows x 128 cols per block) ----------
// out = A[M][K] @ B + bias + rowsc[row]*cvec[col].  outb: bf16 (+optional BN stats,
// optional transposed write out[col*M+row]); outf: fp32.
template <int K>
__global__ __launch_bounds__(256) void k_gemm2(
    const __hip_bfloat16* __restrict__ A, const __hip_bfloat16* __restrict__ Bt,
    const float* __restrict__ bias, const float* __restrict__ rowsc,
    const float* __restrict__ cvec, __hip_bfloat16* __restrict__ outb,
    float* __restrict__ outf, float* __restrict__ gsum, float* __restrict__ gsq, int M,
    int outTrans) {
    constexpr int KS = K / 32;
    constexpr int LDR = K + 8;
    constexpr int ROWU4 = K / 8;
    __shared__ __align__(16) unsigned short Bs[128 * LDR];
    __shared__ float sred[4][128];
    __shared__ float qred[4][128];

    const int t = threadIdx.x;
    const int wv = t >> 6;
    const int lane = t & 63;
    const int mlane = lane & 15;
    const int quad = lane >> 4;
    const int m0 = blockIdx.x * 64;
    const int n0 = blockIdx.y * 128;

    const int arow = m0 + wv * 16 + mlane;
    bf16x8 a[KS];
#pragma unroll
    for (int ks = 0; ks < KS; ks++)
        a[ks] = *(const bf16x8*)(A + (size_t)arow * K + ks * 32 + quad * 8);

#pragma unroll
    for (int i = 0; i < 128 * ROWU4 / 256; i++) {
        int idx = t + i * 256;
        int row = idx / ROWU4;
        int c = idx % ROWU4;
        uint4 v = *(const uint4*)(Bt + (size_t)(n0 + row) * K + c * 8);
        *(uint4*)(Bs + row * LDR + c * 8) = v;
    }
    __syncthreads();

    f32x4 acc[8];
#pragma unroll
    for (int i = 0; i < 8; i++) acc[i] = (f32x4){0.f, 0.f, 0.f, 0.f};

#pragma unroll
    for (int nt = 0; nt < 8; nt++) {
        const unsigned short* bp = Bs + (nt * 16 + mlane) * LDR + quad * 8;
#pragma unroll
        for (int ks = 0; ks < KS; ks++) {
            bf16x8 b = *(const bf16x8*)(bp + ks * 32);
            acc[nt] = __builtin_amdgcn_mfma_f32_16x16x32_bf16(a[ks], b, acc[nt], 0, 0, 0);
        }
    }

    float sr[4];
#pragma unroll
    for (int rr = 0; rr < 4; rr++) {
        int row = m0 + wv * 16 + quad * 4 + rr;
        sr[rr] = (rowsc && row < M) ? rowsc[row] : 0.f;
    }

    if (outb) {
        float sp[8], qp[8];
#pragma unroll
        for (int nt = 0; nt < 8; nt++) {
            int colx = n0 + nt * 16 + mlane;
            float bv = bias ? bias[colx] : 0.f;
            float cv = cvec ? cvec[colx] : 0.f;
            float s = 0.f, q = 0.f;
#pragma unroll
            for (int rr = 0; rr < 4; rr++) {
                int row = m0 + wv * 16 + quad * 4 + rr;
                if (row < M) {
                    float h = acc[nt][rr] + bv + sr[rr] * cv;
                    if (outTrans)
                        outb[(size_t)colx * M + row] = __float2bfloat16(h);
                    else
                        outb[(size_t)row * HID + colx] = __float2bfloat16(h);
                    s += h;
                    q += h * h;
                }
            }
            sp[nt] = s;
            qp[nt] = q;
        }
        if (gsum) {
#pragma unroll
            for (int nt = 0; nt < 8; nt++) {
                sp[nt] += __shfl_xor(sp[nt], 16);
                sp[nt] += __shfl_xor(sp[nt], 32);
                qp[nt] += __shfl_xor(qp[nt], 16);
                qp[nt] += __shfl_xor(qp[nt], 32);
            }
            if (quad == 0) {
#pragma unroll
                for (int nt = 0; nt < 8; nt++) {
                    sred[wv][nt * 16 + mlane] = sp[nt];
                    qred[wv][nt * 16 + mlane] = qp[nt];
                }
            }
            __syncthreads();
            if (t < 128) {
                float ss = sred[0][t] + sred[1][t] + sred[2][t] + sred[3][t];
                float qq = qred[0][t] + qred[1][t] + qred[2][t] + qred[3][t];
                atomicAdd(&gsum[n0 + t], ss);
                atomicAdd(&gsq[n0 + t], qq);
            }
        }
    } else {
#pragma unroll
        for (int nt = 0; nt < 8; nt++) {
            int colx = n0 + nt * 16 + mlane;
            float bv = bias ? bias[colx] : 0.f;
#pragma unroll
            for (int rr = 0; rr < 4; rr++) {
                int row = m0 + wv * 16 + quad * 4 + rr;
                if (row < M) outf[(size_t)row * HID + colx] = acc[nt][rr] + bv;
            }
        }
    }
}

extern "C" void kernel_launch(void* const* d_in, const int* in_sizes, int n_in, void* d_out,
                              int out_size, void* d_ws, size_t ws_size, hipStream_t stream) {
    const float* x = (const float*)d_in[0];
    const int* ei = (const int*)d_in[1];
    const float* W1 = (const float*)d_in[2];
    const float* b1 = (const float*)d_in[3];
    const float* g1 = (const float*)d_in[4];
    const float* be1 = (const float*)d_in[5];
    const float* W2 = (const float*)d_in[6];
    const float* b2 = (const float*)d_in[7];
    const float* g2 = (const float*)d_in[8];
    const float* be2 = (const float*)d_in[9];
    const float* Wfc = (const float*)d_in[10];
    const float* bfc = (const float*)d_in[11];
    float* out = (float*)d_out;

    const int N = in_sizes[0] / NFEAT;  // 50000
    const int E = in_sizes[1] / 2;      // 800000
    const float invN = 1.0f / (float)N;

    char* ws = (char*)d_ws;
    size_t off = 0;
    auto alloc = [&](size_t bytes) -> void* {
        void* p = ws + off;
        off += (bytes + 255) & ~(size_t)255;
        return p;
    };
    int* row_cnt = (int*)alloc((size_t)N * 4);
    int* partial = (int*)alloc((size_t)N * 4);
    int* row_start = (int*)alloc((size_t)N * 4);
    int* blk = (int*)alloc(1024);
    float* dinv = (float*)alloc((size_t)N * 4);
    int* rank = (int*)alloc((size_t)E * 4);
    int* col_idx = (int*)alloc((size_t)E * 4);
    float* stats = (float*)alloc(640 * 4);  // gs2 sum(256)+sq(256), colsum(128)
    float* G = (float*)alloc(16384 * 4);
    float* u = (float*)alloc(256 * 4);
    float* c2v = (float*)alloc(256 * 4);
    float* cf = (float*)alloc(256 * 4);
    float* svec = (float*)alloc((size_t)(N + 64) * 4);
    __hip_bfloat16* Wt2 = (__hip_bfloat16*)alloc(65536 * 2);
    __hip_bfloat16* Wtf = (__hip_bfloat16*)alloc(65536 * 2);
    __hip_bfloat16* W1s = (__hip_bfloat16*)alloc(32768 * 2);
    __hip_bfloat16* W12t = (__hip_bfloat16*)alloc(32768 * 2);
    __hip_bfloat16* xs = (__hip_bfloat16*)alloc((size_t)(N + 64) * 128 * 2);  // reused as r
    __hip_bfloat16* aggX = (__hip_bfloat16*)alloc((size_t)N * 128 * 2);
    __hip_bfloat16* p = (__hip_bfloat16*)alloc((size_t)N * 128 * 2);
    // Gpart (224*16384 f = 14.7 MB) reused as h2 ((N+64)*256 bf16 = 25.7 MB): alloc max
    float* Gpart = (float*)alloc((size_t)(N + 64) * 256 * 2);
    __hip_bfloat16* r = xs;                  // xs dead after spmm1
    __hip_bfloat16* h2 = (__hip_bfloat16*)Gpart;  // Gpart dead after gramred

    hipMemsetAsync(row_cnt, 0, (size_t)N * 4, stream);
    hipMemsetAsync(stats, 0, 640 * 4, stream);

    // CSR build
    k_count<<<(E + 255) / 256, 256, 0, stream>>>(ei, E, row_cnt, rank);
    int nblk = (N + 255) / 256;
    k_scan1<<<nblk, 256, 0, stream>>>(row_cnt, N, partial, blk);
    k_scan2<<<1, 256, 0, stream>>>(blk, nblk);
    k_finalize<<<nblk, 256, 0, stream>>>(partial, blk, row_cnt, N, row_start, dinv);
    k_fill<<<(E + 255) / 256, 256, 0, stream>>>(ei, rank, row_start, E, col_idx);

    k_transpose2<<<512, 256, 0, stream>>>(W2, Wfc, Wt2, Wtf);
    k_scale_cast<<<(N * 128 / 4 + 255) / 256, 256, 0, stream>>>(x, dinv, xs, 5, N * 128 / 4);

    int sg = (N + 3) / 4;
    // both aggregations on 128 channels
    k_spmm1<<<sg, 256, 0, stream>>>(xs, row_start, row_cnt, col_idx, dinv, aggX, p, N);
    k_spmm2<<<sg, 256, 0, stream>>>(p, row_start, row_cnt, col_idx, dinv, r, svec, N);

    // BN1 stats via Gram of aggX
    k_colsum<<<128, 256, 0, stream>>>(aggX, N, stats + 512);
    k_gram<<<224, 256, 0, stream>>>(aggX, N, Gpart);
    k_gramred<<<64, 256, 0, stream>>>(Gpart, G, 224);
    k_bncoef<<<256, 128, 0, stream>>>(G, stats + 512, W1, b1, g1, be1, invN, u, W1s);
    k_c2<<<1, 256, 0, stream>>>(u, W2, c2v);
    // W12^T = (W1 diag(sc1) W2)^T  (transposed write, 256x128 bf16)
    k_gemm2<256><<<dim3(2, 2), 256, 0, stream>>>(W1s, Wt2, nullptr, nullptr, nullptr, W12t,
                                                 nullptr, nullptr, nullptr, 128, 1);
    // h2 = r @ W12 + s*c2 + b2, fused BN2 stats
    dim3 gg((N + 63) / 64, 2);
    k_gemm2<128><<<gg, 256, 0, stream>>>(r, W12t, b2, svec, c2v, h2, nullptr, stats, stats + 256,
                                         N, 0);
    // fold BN2 into final weights, then out = h2 @ (sc2*Wfc) + cf
    k_bn2fold<<<1, 256, 0, stream>>>(stats, stats + 256, g2, be2, Wfc, bfc, invN, Wtf, cf);
    k_gemm2<256><<<gg, 256, 0, stream>>>(h2, Wtf, cf, nullptr, nullptr, nullptr, out, nullptr,
                                         nullptr, N, 0);
}